// Round 9
// baseline (865.114 us; speedup 1.0000x reference)
//
#include <hip/hip_runtime.h>
#include <hip/hip_bf16.h>
#include <hip/hip_cooperative_groups.h>

namespace cg = cooperative_groups;

#define NN   50000
#define NE   800000
#define NB   196    // ceil(NN/256) for fallback scan kernels
#define GB   1024   // cooperative grid blocks

typedef __attribute__((ext_vector_type(8))) short short8;
typedef __attribute__((ext_vector_type(4))) float f32x4;

static __device__ __forceinline__ ushort f2bf(float f) {
    union { float f; unsigned u; } v; v.f = f;
    unsigned r = v.u + 0x7fffu + ((v.u >> 16) & 1u);   // round-to-nearest-even
    return (ushort)(r >> 16);
}
static __device__ __forceinline__ float bf2f(ushort h) {
    union { unsigned u; float f; } v; v.u = ((unsigned)h) << 16;
    return v.f;
}

static __device__ __forceinline__ void weight_prep(
    int gid,
    const float* __restrict__ Wl0, const float* __restrict__ Wr0,
    const float* __restrict__ Wl1, const float* __restrict__ Wr1,
    ushort* __restrict__ wbt0, ushort* __restrict__ wbt1)
{
    {   // dense0 image
        int c = gid;
        int n  = c >> 4;
        int kc = (c & 15) * 8;
        const float* wsrc = (kc < 64) ? (Wl0 + n * 64 + kc) : (Wr0 + n * 64 + (kc - 64));
        float4 f0 = *(const float4*)(wsrc);
        float4 f1 = *(const float4*)(wsrc + 4);
        short8 v;
        v[0] = f2bf(f0.x); v[1] = f2bf(f0.y); v[2] = f2bf(f0.z); v[3] = f2bf(f0.w);
        v[4] = f2bf(f1.x); v[5] = f2bf(f1.y); v[6] = f2bf(f1.z); v[7] = f2bf(f1.w);
        int byte = (n * 256 + kc * 2) ^ ((n & 7) << 4);
        *(short8*)((char*)wbt0 + byte) = v;
    }
    #pragma unroll
    for (int rep = 0; rep < 2; ++rep) {   // dense1 image
        int c = gid + rep * 2048;
        int n  = c >> 5;
        int kc = (c & 31) * 8;
        const float* wsrc = (kc < 128) ? (Wl1 + n * 128 + kc) : (Wr1 + n * 128 + (kc - 128));
        float4 f0 = *(const float4*)(wsrc);
        float4 f1 = *(const float4*)(wsrc + 4);
        short8 v;
        v[0] = f2bf(f0.x); v[1] = f2bf(f0.y); v[2] = f2bf(f0.z); v[3] = f2bf(f0.w);
        v[4] = f2bf(f1.x); v[5] = f2bf(f1.y); v[6] = f2bf(f1.z); v[7] = f2bf(f1.w);
        int byte = (n * 512 + kc * 2) ^ ((n & 7) << 4);
        *(short8*)((char*)wbt1 + byte) = v;
    }
}

// ============ cooperative all-in-one CSR build ============
__global__ __launch_bounds__(256, 4) void build_k(
    const int* __restrict__ src, const int* __restrict__ dst,
    int* __restrict__ deg, int* __restrict__ rank,
    const float* __restrict__ x, ushort* __restrict__ xb,
    const float* __restrict__ Wl0, const float* __restrict__ Wr0,
    const float* __restrict__ Wl1, const float* __restrict__ Wr1,
    ushort* __restrict__ wbt0, ushort* __restrict__ wbt1,
    int* __restrict__ bsum, int* __restrict__ boff,
    int* __restrict__ rowptr, int* __restrict__ nbr)
{
    __shared__ int s[256];
    cg::grid_group grid = cg::this_grid();
    const int gid  = blockIdx.x * 256 + threadIdx.x;
    const int nthr = GB * 256;               // 262144
    const int NPB  = (NN + GB - 1) / GB;     // 49 nodes per block

    // ---- phase 0: weight images, x->bf16, zero deg ----
    if (gid < 2048)
        weight_prep(gid, Wl0, Wr0, Wl1, Wr1, wbt0, wbt1);
    for (int i = gid; i < NE; i += nthr) {   // NE float4 groups == NN*64/4
        int base = i * 4;
        float4 f = *(const float4*)(x + base);
        ushort4 o;
        o.x = f2bf(f.x); o.y = f2bf(f.y); o.z = f2bf(f.z); o.w = f2bf(f.w);
        *(ushort4*)(xb + base) = o;
    }
    for (int i = gid; i < NN; i += nthr) deg[i] = 0;
    __threadfence();
    grid.sync();

    // ---- phase 1: count + rank ----
    for (int e = gid; e < NE; e += nthr)
        rank[e] = atomicAdd(&deg[dst[e]], 1);
    __threadfence();
    grid.sync();

    // ---- phase 2: per-block partial sums over NPB nodes ----
    if (threadIdx.x < 64) {
        int t  = threadIdx.x;
        int b0 = blockIdx.x * NPB;
        int v  = (t < NPB && b0 + t < NN) ? deg[b0 + t] : 0;
        #pragma unroll
        for (int off = 32; off > 0; off >>= 1) v += __shfl_xor(v, off, 64);
        if (t == 0) bsum[blockIdx.x] = v;
    }
    __threadfence();
    grid.sync();

    // ---- phase 3: block 0 exclusive-scans the GB block sums ----
    if (blockIdx.x == 0) {
        int t = threadIdx.x;
        const int C = GB / 256;              // 4
        int vals[C];
        int loc = 0;
        #pragma unroll
        for (int j = 0; j < C; ++j) { vals[j] = bsum[t * C + j]; loc += vals[j]; }
        s[t] = loc;
        __syncthreads();
        for (int off = 1; off < 256; off <<= 1) {
            int add = (t >= off) ? s[t - off] : 0;
            __syncthreads();
            s[t] += add;
            __syncthreads();
        }
        int run = (t == 0) ? 0 : s[t - 1];
        #pragma unroll
        for (int j = 0; j < C; ++j) { boff[t * C + j] = run; run += vals[j]; }
        if (t == 0) rowptr[NN] = NE;
        __threadfence();
    }
    grid.sync();

    // ---- phase 4: per-block exclusive scan of its NPB deg values -> rowptr ----
    if (threadIdx.x < 64) {
        int t  = threadIdx.x;
        int b0 = blockIdx.x * NPB;
        bool on = (t < NPB && b0 + t < NN);
        int dv = on ? deg[b0 + t] : 0;
        int v  = dv;
        #pragma unroll
        for (int off = 1; off < 64; off <<= 1) {
            int u = __shfl_up(v, off, 64);
            if (t >= off) v += u;
        }
        if (on) rowptr[b0 + t] = boff[blockIdx.x] + (v - dv);
    }
    __threadfence();
    grid.sync();

    // ---- phase 5: deterministic fill ----
    for (int e = gid; e < NE; e += nthr)
        nbr[rowptr[dst[e]] + rank[e]] = src[e];
}

// ============ fallback path (R8 kernels) ============
__global__ __launch_bounds__(256) void count_k(
    const int* __restrict__ dst, int* __restrict__ deg,
    int* __restrict__ rank,
    const float* __restrict__ x, ushort* __restrict__ xb,
    const float* __restrict__ Wl0, const float* __restrict__ Wr0,
    const float* __restrict__ Wl1, const float* __restrict__ Wr1,
    ushort* __restrict__ wbt0, ushort* __restrict__ wbt1)
{
    int gid = blockIdx.x * 256 + threadIdx.x;
    if (gid < 2048)
        weight_prep(gid, Wl0, Wr0, Wl1, Wr1, wbt0, wbt1);
    int base = gid * 4;
    float4 f = *(const float4*)(x + base);
    ushort4 o;
    o.x = f2bf(f.x); o.y = f2bf(f.y); o.z = f2bf(f.z); o.w = f2bf(f.w);
    *(ushort4*)(xb + base) = o;
    int d = dst[gid];
    rank[gid] = atomicAdd(&deg[d], 1);
}

__global__ __launch_bounds__(256) void partial_k(
    const int* __restrict__ deg, int* __restrict__ bsum)
{
    int gid = blockIdx.x * 256 + threadIdx.x;
    int v = (gid < NN) ? deg[gid] : 0;
    #pragma unroll
    for (int off = 32; off > 0; off >>= 1) v += __shfl_xor(v, off, 64);
    __shared__ int wsum[4];
    if ((threadIdx.x & 63) == 0) wsum[threadIdx.x >> 6] = v;
    __syncthreads();
    if (threadIdx.x == 0)
        bsum[blockIdx.x] = wsum[0] + wsum[1] + wsum[2] + wsum[3];
}

__global__ __launch_bounds__(256) void emit_k(
    const int* __restrict__ deg, const int* __restrict__ bsum,
    int* __restrict__ rowptr)
{
    __shared__ int s[256], sb[256];
    int tid = threadIdx.x;
    int gid = blockIdx.x * 256 + tid;
    int v  = (gid < NN) ? deg[gid] : 0;
    int bv = (tid < NB) ? bsum[tid] : 0;
    s[tid] = v; sb[tid] = bv;
    __syncthreads();
    for (int off = 1; off < 256; off <<= 1) {
        int a1 = (tid >= off) ? s[tid - off] : 0;
        int a2 = (tid >= off) ? sb[tid - off] : 0;
        __syncthreads();
        s[tid] += a1; sb[tid] += a2;
        __syncthreads();
    }
    int boff = (blockIdx.x == 0) ? 0 : sb[blockIdx.x - 1];
    if (gid < NN) rowptr[gid] = boff + s[tid] - v;
    if (blockIdx.x == 0 && tid == 0) rowptr[NN] = NE;
}

__global__ __launch_bounds__(256) void fill_k(
    const int* __restrict__ src, const int* __restrict__ dst,
    const int* __restrict__ rowptr, const int* __restrict__ rank,
    int* __restrict__ nbr)
{
    int e = blockIdx.x * 256 + threadIdx.x;
    int d = dst[e];
    nbr[rowptr[d] + rank[e]] = src[e];
}

// ---------------- gather0: 8 groups x 8 lanes, 16B/lane ----------------
__global__ __launch_bounds__(256) void gather0_k(
    const ushort* __restrict__ xb, const int* __restrict__ rowptr,
    const int* __restrict__ nbr, ushort* __restrict__ agg0)
{
    int gid  = blockIdx.x * 256 + threadIdx.x;
    int lane = gid & 63;
    int node = gid >> 6;
    if (node >= NN) return;
    int g   = lane >> 3;
    int sub = lane & 7;
    int b = rowptr[node], e2 = rowptr[node + 1];
    float acc[8];
    #pragma unroll
    for (int j = 0; j < 8; ++j) acc[j] = 0.f;

    int e = b;
    for (; e + 16 <= e2; e += 16) {
        int sA = nbr[e + g];
        int sB = nbr[e + 8 + g];
        short8 vA = *(const short8*)(xb + sA * 64 + sub * 8);
        short8 vB = *(const short8*)(xb + sB * 64 + sub * 8);
        #pragma unroll
        for (int j = 0; j < 8; ++j)
            acc[j] += bf2f((ushort)vA[j]) + bf2f((ushort)vB[j]);
    }
    for (; e < e2; e += 8) {
        int eg = e + g;
        bool valid = eg < e2;
        int s = valid ? nbr[eg] : 0;
        short8 v = *(const short8*)(xb + s * 64 + sub * 8);
        float m = valid ? 1.f : 0.f;
        #pragma unroll
        for (int j = 0; j < 8; ++j)
            acc[j] += m * bf2f((ushort)v[j]);
    }

    #pragma unroll
    for (int j = 0; j < 8; ++j) {
        float t = acc[j];
        t += __shfl_xor(t, 8, 64);
        t += __shfl_xor(t, 16, 64);
        t += __shfl_xor(t, 32, 64);
        acc[j] = t;
    }
    if (g == 0) {
        float inv = 1.0f / fmaxf((float)(e2 - b), 1.0f);
        short8 o;
        #pragma unroll
        for (int j = 0; j < 8; ++j) o[j] = (short)f2bf(acc[j] * inv);
        *(short8*)(agg0 + node * 64 + sub * 8) = o;
    }
}

// ---------------- gather1: 4 groups x 16 lanes, 16B/lane ----------------
__global__ __launch_bounds__(256) void gather1_k(
    const ushort* __restrict__ h0, const int* __restrict__ rowptr,
    const int* __restrict__ nbr, ushort* __restrict__ agg1)
{
    int gid  = blockIdx.x * 256 + threadIdx.x;
    int lane = gid & 63;
    int node = gid >> 6;
    if (node >= NN) return;
    int g   = lane >> 4;
    int sub = lane & 15;
    int b = rowptr[node], e2 = rowptr[node + 1];
    float acc[8];
    #pragma unroll
    for (int j = 0; j < 8; ++j) acc[j] = 0.f;

    int e = b;
    for (; e + 8 <= e2; e += 8) {
        int sA = nbr[e + g];
        int sB = nbr[e + 4 + g];
        short8 vA = *(const short8*)(h0 + sA * 128 + sub * 8);
        short8 vB = *(const short8*)(h0 + sB * 128 + sub * 8);
        #pragma unroll
        for (int j = 0; j < 8; ++j)
            acc[j] += bf2f((ushort)vA[j]) + bf2f((ushort)vB[j]);
    }
    for (; e < e2; e += 4) {
        int eg = e + g;
        bool valid = eg < e2;
        int s = valid ? nbr[eg] : 0;
        short8 v = *(const short8*)(h0 + s * 128 + sub * 8);
        float m = valid ? 1.f : 0.f;
        #pragma unroll
        for (int j = 0; j < 8; ++j)
            acc[j] += m * bf2f((ushort)v[j]);
    }

    #pragma unroll
    for (int j = 0; j < 8; ++j) {
        float t = acc[j];
        t += __shfl_xor(t, 16, 64);
        t += __shfl_xor(t, 32, 64);
        acc[j] = t;
    }
    if (g == 0) {
        float inv = 1.0f / fmaxf((float)(e2 - b), 1.0f);
        short8 o;
        #pragma unroll
        for (int j = 0; j < 8; ++j) o[j] = (short)f2bf(acc[j] * inv);
        *(short8*)(agg1 + node * 128 + sub * 8) = o;
    }
}

// ---------------- dense0: h0 = relu([agg0|x] @ [Wl0;Wr0]^T + bl0), MFMA ----------------
__global__ __launch_bounds__(256) void dense0_k(
    const ushort* __restrict__ xb, const ushort* __restrict__ agg0,
    const ushort* __restrict__ wbt0, const float* __restrict__ bl,
    ushort* __restrict__ h0)
{
    __shared__ ushort bt[128 * 128];
    __shared__ float  bl_s[128];

    #pragma unroll
    for (int c = 0; c < 8; ++c) {
        int i = threadIdx.x + c * 256;
        ((short8*)bt)[i] = ((const short8*)wbt0)[i];
    }
    if (threadIdx.x < 128) bl_s[threadIdx.x] = bl[threadIdx.x];
    __syncthreads();

    int w = threadIdx.x >> 6, l = threadIdx.x & 63;
    int l15 = l & 15, hi = l >> 4;
    int row  = blockIdx.x * 64 + w * 16 + l15;
    int rowc = row < NN ? row : 0;

    short8 a[4];
    a[0] = *(const short8*)(agg0 + rowc * 64 + hi * 8);
    a[1] = *(const short8*)(agg0 + rowc * 64 + 32 + hi * 8);
    a[2] = *(const short8*)(xb + rowc * 64 + hi * 8);
    a[3] = *(const short8*)(xb + rowc * 64 + 32 + hi * 8);

    f32x4 acc[8];
    #pragma unroll
    for (int nt = 0; nt < 8; ++nt) acc[nt] = (f32x4){0.f, 0.f, 0.f, 0.f};

    #pragma unroll
    for (int ks = 0; ks < 4; ++ks) {
        #pragma unroll
        for (int nt = 0; nt < 8; ++nt) {
            int byte = ((nt * 16 + l15) * 256 + (ks * 32 + hi * 8) * 2) ^ ((l15 & 7) << 4);
            short8 bfr = *(const short8*)((const char*)bt + byte);
            acc[nt] = __builtin_amdgcn_mfma_f32_16x16x32_bf16(a[ks], bfr, acc[nt], 0, 0, 0);
        }
    }

    int rowbase = blockIdx.x * 64 + w * 16 + hi * 4;
    #pragma unroll
    for (int r = 0; r < 4; ++r) {
        int ro = rowbase + r;
        if (ro < NN) {
            #pragma unroll
            for (int nt = 0; nt < 8; ++nt) {
                int col = nt * 16 + l15;
                float v = fmaxf(acc[nt][r] + bl_s[col], 0.f);
                h0[ro * 128 + col] = f2bf(v);
            }
        }
    }
}

// ---------------- dense1 + fc fused ----------------
__global__ __launch_bounds__(256) void dense1_k(
    const ushort* __restrict__ h0, const ushort* __restrict__ agg1,
    const ushort* __restrict__ wbt1, const float* __restrict__ bl,
    const float* __restrict__ Wfc, const float* __restrict__ bfc,
    float* __restrict__ out)
{
    __shared__ ushort bt[256 * 128];
    __shared__ float  bl_s[128];
    __shared__ float  wfc_s[256];

    #pragma unroll
    for (int c = 0; c < 16; ++c) {
        int i = threadIdx.x + c * 256;
        ((short8*)bt)[i] = ((const short8*)wbt1)[i];
    }
    if (threadIdx.x < 128) bl_s[threadIdx.x] = bl[threadIdx.x];
    if (threadIdx.x < 256) wfc_s[threadIdx.x] = Wfc[threadIdx.x];
    __syncthreads();

    int w = threadIdx.x >> 6, l = threadIdx.x & 63;
    int l15 = l & 15, hi = l >> 4;
    int row  = blockIdx.x * 64 + w * 16 + l15;
    int rowc = row < NN ? row : 0;

    short8 a[8];
    #pragma unroll
    for (int ks = 0; ks < 4; ++ks)
        a[ks] = *(const short8*)(agg1 + rowc * 128 + ks * 32 + hi * 8);
    #pragma unroll
    for (int ks = 0; ks < 4; ++ks)
        a[4 + ks] = *(const short8*)(h0 + rowc * 128 + ks * 32 + hi * 8);

    f32x4 acc[8];
    #pragma unroll
    for (int nt = 0; nt < 8; ++nt) acc[nt] = (f32x4){0.f, 0.f, 0.f, 0.f};

    #pragma unroll
    for (int ks = 0; ks < 8; ++ks) {
        #pragma unroll
        for (int nt = 0; nt < 8; ++nt) {
            int byte = ((nt * 16 + l15) * 512 + (ks * 32 + hi * 8) * 2) ^ ((l15 & 7) << 4);
            short8 bfr = *(const short8*)((const char*)bt + byte);
            acc[nt] = __builtin_amdgcn_mfma_f32_16x16x32_bf16(a[ks], bfr, acc[nt], 0, 0, 0);
        }
    }

    int rowbase = blockIdx.x * 64 + w * 16 + hi * 4;
    #pragma unroll
    for (int r = 0; r < 4; ++r) {
        float p0 = 0.f, p1 = 0.f;
        #pragma unroll
        for (int nt = 0; nt < 8; ++nt) {
            int col = nt * 16 + l15;
            float h1 = fmaxf(acc[nt][r] + bl_s[col], 0.f);
            p0 += h1 * wfc_s[col];
            p1 += h1 * wfc_s[128 + col];
        }
        p0 += __shfl_xor(p0, 1, 64); p0 += __shfl_xor(p0, 2, 64);
        p0 += __shfl_xor(p0, 4, 64); p0 += __shfl_xor(p0, 8, 64);
        p1 += __shfl_xor(p1, 1, 64); p1 += __shfl_xor(p1, 2, 64);
        p1 += __shfl_xor(p1, 4, 64); p1 += __shfl_xor(p1, 8, 64);
        int ro = rowbase + r;
        if (l15 == 0 && ro < NN) {
            float2 o; o.x = p0 + bfc[0]; o.y = p1 + bfc[1];
            *(float2*)(out + ro * 2) = o;
        }
    }
}

extern "C" void kernel_launch(void* const* d_in, const int* in_sizes, int n_in,
                              void* d_out, int out_size, void* d_ws, size_t ws_size,
                              hipStream_t stream)
{
    const float* x   = (const float*)d_in[0];
    const int*   ei  = (const int*)d_in[1];
    const float* Wl0 = (const float*)d_in[2];
    const float* bl0 = (const float*)d_in[3];
    const float* Wr0 = (const float*)d_in[4];
    const float* Wl1 = (const float*)d_in[5];
    const float* bl1 = (const float*)d_in[6];
    const float* Wr1 = (const float*)d_in[7];
    const float* Wfc = (const float*)d_in[8];
    const float* bfc = (const float*)d_in[9];
    float* out = (float*)d_out;

    const int* src = ei;
    const int* dst = ei + NE;

    // ws layout (bytes):
    //   deg    @ 0          (200,000)
    //   rowptr @ 200,000    (200,004)
    //   rank   @ 400,004    (3,200,000)
    //   nbr    @ 3,600,004  (3,200,000)
    //   aggB   @ 6,800,016  (12,800,000)
    //   h0B    @ 19,600,016 (12,800,000)
    //   bsum   @ 32,400,016 (4,096)
    //   boff   @ 32,404,112 (4,096)
    //   xb     @ 32,408,224 (6,400,000)
    //   wbt0   @ 38,808,224 (32,768)
    //   wbt1   @ 38,840,992 (65,536)
    char*   ws     = (char*)d_ws;
    int*    deg    = (int*)(ws);
    int*    rowptr = (int*)(ws + 200000);
    int*    rank   = (int*)(ws + 400004);
    int*    nbr    = (int*)(ws + 3600004);
    ushort* aggB   = (ushort*)(ws + 6800016);
    ushort* h0B    = (ushort*)(ws + 19600016);
    int*    bsum   = (int*)(ws + 32400016);
    int*    boff   = (int*)(ws + 32404112);
    ushort* xb     = (ushort*)(ws + 32408224);
    ushort* wbt0   = (ushort*)(ws + 38808224);
    ushort* wbt1   = (ushort*)(ws + 38840992);

    // ---- CSR build: one cooperative kernel; fallback to 5-kernel chain ----
    void* args[] = {
        (void*)&src, (void*)&dst, (void*)&deg, (void*)&rank,
        (void*)&x, (void*)&xb,
        (void*)&Wl0, (void*)&Wr0, (void*)&Wl1, (void*)&Wr1,
        (void*)&wbt0, (void*)&wbt1,
        (void*)&bsum, (void*)&boff, (void*)&rowptr, (void*)&nbr
    };
    hipError_t cerr = hipLaunchCooperativeKernel(
        (const void*)build_k, dim3(GB), dim3(256), args, 0, stream);
    if (cerr != hipSuccess) {
        hipMemsetAsync(deg, 0, 200000, stream);
        count_k  <<<3125, 256, 0, stream>>>(dst, deg, rank, x, xb,
                                            Wl0, Wr0, Wl1, Wr1, wbt0, wbt1);
        partial_k<<<NB, 256, 0, stream>>>(deg, bsum);
        emit_k   <<<NB, 256, 0, stream>>>(deg, bsum, rowptr);
        fill_k   <<<3125, 256, 0, stream>>>(src, dst, rowptr, rank, nbr);
    }

    gather0_k<<<12500, 256, 0, stream>>>(xb, rowptr, nbr, aggB);
    dense0_k <<<782, 256, 0, stream>>>(xb, aggB, wbt0, bl0, h0B);
    gather1_k<<<12500, 256, 0, stream>>>(h0B, rowptr, nbr, aggB);
    dense1_k <<<782, 256, 0, stream>>>(h0B, aggB, wbt1, bl1, Wfc, bfc, out);
}

// Round 10
// 149.936 us; speedup vs baseline: 5.7699x; 5.7699x over previous
//
#include <hip/hip_runtime.h>
#include <hip/hip_bf16.h>

#define NN   50000
#define NE   800000
#define NB   196   // ceil(NN/256)

typedef __attribute__((ext_vector_type(8))) short short8;
typedef __attribute__((ext_vector_type(4))) float f32x4;

static __device__ __forceinline__ ushort f2bf(float f) {
    union { float f; unsigned u; } v; v.f = f;
    unsigned r = v.u + 0x7fffu + ((v.u >> 16) & 1u);   // round-to-nearest-even
    return (ushort)(r >> 16);
}
static __device__ __forceinline__ float bf2f(ushort h) {
    union { unsigned u; float f; } v; v.u = ((unsigned)h) << 16;
    return v.f;
}

// ---------------- count (+rank) + x->bf16 + weight-image prep ----------------
__global__ __launch_bounds__(256) void count_k(
    const int* __restrict__ dst, int* __restrict__ deg,
    int* __restrict__ rank,
    const float* __restrict__ x, ushort* __restrict__ xb,
    const float* __restrict__ Wl0, const float* __restrict__ Wr0,
    const float* __restrict__ Wl1, const float* __restrict__ Wr1,
    ushort* __restrict__ wbt0, ushort* __restrict__ wbt1)
{
    int gid = blockIdx.x * 256 + threadIdx.x;

    if (gid < 2048) {
        {   // dense0 image
            int c = gid;
            int n  = c >> 4;
            int kc = (c & 15) * 8;
            const float* wsrc = (kc < 64) ? (Wl0 + n * 64 + kc) : (Wr0 + n * 64 + (kc - 64));
            float4 f0 = *(const float4*)(wsrc);
            float4 f1 = *(const float4*)(wsrc + 4);
            short8 v;
            v[0] = f2bf(f0.x); v[1] = f2bf(f0.y); v[2] = f2bf(f0.z); v[3] = f2bf(f0.w);
            v[4] = f2bf(f1.x); v[5] = f2bf(f1.y); v[6] = f2bf(f1.z); v[7] = f2bf(f1.w);
            int byte = (n * 256 + kc * 2) ^ ((n & 7) << 4);
            *(short8*)((char*)wbt0 + byte) = v;
        }
        #pragma unroll
        for (int rep = 0; rep < 2; ++rep) {   // dense1 image
            int c = gid + rep * 2048;
            int n  = c >> 5;
            int kc = (c & 31) * 8;
            const float* wsrc = (kc < 128) ? (Wl1 + n * 128 + kc) : (Wr1 + n * 128 + (kc - 128));
            float4 f0 = *(const float4*)(wsrc);
            float4 f1 = *(const float4*)(wsrc + 4);
            short8 v;
            v[0] = f2bf(f0.x); v[1] = f2bf(f0.y); v[2] = f2bf(f0.z); v[3] = f2bf(f0.w);
            v[4] = f2bf(f1.x); v[5] = f2bf(f1.y); v[6] = f2bf(f1.z); v[7] = f2bf(f1.w);
            int byte = (n * 512 + kc * 2) ^ ((n & 7) << 4);
            *(short8*)((char*)wbt1 + byte) = v;
        }
    }

    int base = gid * 4;
    float4 f = *(const float4*)(x + base);
    ushort4 o;
    o.x = f2bf(f.x); o.y = f2bf(f.y); o.z = f2bf(f.z); o.w = f2bf(f.w);
    *(ushort4*)(xb + base) = o;

    int d = dst[gid];
    rank[gid] = atomicAdd(&deg[d], 1);
}

// ---- single-pass scan: per-block scan + decoupled lookback across 196 blocks ----
// state[b]: bits63..62 = flag (0 invalid, 1 aggregate, 2 inclusive), low 32 = value
__global__ __launch_bounds__(256) void scan_k(
    const int* __restrict__ deg, unsigned long long* state,
    int* __restrict__ rowptr)
{
    __shared__ int s[256];
    __shared__ int sboff;
    int tid = threadIdx.x, bid = blockIdx.x;
    int gid = bid * 256 + tid;
    int v = (gid < NN) ? deg[gid] : 0;
    s[tid] = v;
    __syncthreads();
    for (int off = 1; off < 256; off <<= 1) {
        int a = (tid >= off) ? s[tid - off] : 0;
        __syncthreads();
        s[tid] += a;
        __syncthreads();
    }
    if (tid == 0) {
        int total = s[255];
        atomicExch(&state[bid], (1ull << 62) | (unsigned)total);
        int prefix = 0;
        for (int j = bid - 1; j >= 0; --j) {
            unsigned long long st;
            do { st = atomicAdd(&state[j], 0ull); } while ((st >> 62) == 0);
            prefix += (int)(st & 0xffffffffu);
            if ((st >> 62) == 2ull) break;
        }
        atomicExch(&state[bid], (2ull << 62) | (unsigned)(prefix + s[255]));
        sboff = prefix;
    }
    __syncthreads();
    int boff = sboff;
    if (gid < NN) rowptr[gid] = boff + s[tid] - v;
    if (gid == 0) rowptr[NN] = NE;
}

// deterministic fill: position = rowptr[dst] + rank, no atomics
__global__ __launch_bounds__(256) void fill_k(
    const int* __restrict__ src, const int* __restrict__ dst,
    const int* __restrict__ rowptr, const int* __restrict__ rank,
    int* __restrict__ nbr)
{
    int e = blockIdx.x * 256 + threadIdx.x;
    int d = dst[e];
    nbr[rowptr[d] + rank[e]] = src[e];
}

// ---------------- gather0: 8 groups x 8 lanes, 16B/lane, 16 edges in flight ----------------
__global__ __launch_bounds__(256) void gather0_k(
    const ushort* __restrict__ xb, const int* __restrict__ rowptr,
    const int* __restrict__ nbr, ushort* __restrict__ agg0)
{
    int gid  = blockIdx.x * 256 + threadIdx.x;
    int lane = gid & 63;
    int node = gid >> 6;
    if (node >= NN) return;
    int g   = lane >> 3;
    int sub = lane & 7;
    int b = rowptr[node], e2 = rowptr[node + 1];
    float acc[8];
    #pragma unroll
    for (int j = 0; j < 8; ++j) acc[j] = 0.f;

    int e = b;
    for (; e + 16 <= e2; e += 16) {
        int sA = nbr[e + g];
        int sB = nbr[e + 8 + g];
        short8 vA = *(const short8*)(xb + sA * 64 + sub * 8);
        short8 vB = *(const short8*)(xb + sB * 64 + sub * 8);
        #pragma unroll
        for (int j = 0; j < 8; ++j)
            acc[j] += bf2f((ushort)vA[j]) + bf2f((ushort)vB[j]);
    }
    for (; e < e2; e += 8) {
        int eg = e + g;
        bool valid = eg < e2;
        int s = valid ? nbr[eg] : 0;
        short8 v = *(const short8*)(xb + s * 64 + sub * 8);
        float m = valid ? 1.f : 0.f;
        #pragma unroll
        for (int j = 0; j < 8; ++j)
            acc[j] += m * bf2f((ushort)v[j]);
    }

    #pragma unroll
    for (int j = 0; j < 8; ++j) {
        float t = acc[j];
        t += __shfl_xor(t, 8, 64);
        t += __shfl_xor(t, 16, 64);
        t += __shfl_xor(t, 32, 64);
        acc[j] = t;
    }
    if (g == 0) {
        float inv = 1.0f / fmaxf((float)(e2 - b), 1.0f);
        short8 o;
        #pragma unroll
        for (int j = 0; j < 8; ++j) o[j] = (short)f2bf(acc[j] * inv);
        *(short8*)(agg0 + node * 64 + sub * 8) = o;
    }
}

// ---------------- gather1: 4 groups x 16 lanes, 16B/lane, 16 edges in flight ----------------
__global__ __launch_bounds__(256) void gather1_k(
    const ushort* __restrict__ h0, const int* __restrict__ rowptr,
    const int* __restrict__ nbr, ushort* __restrict__ agg1)
{
    int gid  = blockIdx.x * 256 + threadIdx.x;
    int lane = gid & 63;
    int node = gid >> 6;
    if (node >= NN) return;
    int g   = lane >> 4;
    int sub = lane & 15;
    int b = rowptr[node], e2 = rowptr[node + 1];
    float acc[8];
    #pragma unroll
    for (int j = 0; j < 8; ++j) acc[j] = 0.f;

    int e = b;
    for (; e + 16 <= e2; e += 16) {
        int sA = nbr[e + g];
        int sB = nbr[e + 4 + g];
        int sC = nbr[e + 8 + g];
        int sD = nbr[e + 12 + g];
        short8 vA = *(const short8*)(h0 + sA * 128 + sub * 8);
        short8 vB = *(const short8*)(h0 + sB * 128 + sub * 8);
        short8 vC = *(const short8*)(h0 + sC * 128 + sub * 8);
        short8 vD = *(const short8*)(h0 + sD * 128 + sub * 8);
        #pragma unroll
        for (int j = 0; j < 8; ++j)
            acc[j] += (bf2f((ushort)vA[j]) + bf2f((ushort)vB[j]))
                    + (bf2f((ushort)vC[j]) + bf2f((ushort)vD[j]));
    }
    for (; e < e2; e += 4) {
        int eg = e + g;
        bool valid = eg < e2;
        int s = valid ? nbr[eg] : 0;
        short8 v = *(const short8*)(h0 + s * 128 + sub * 8);
        float m = valid ? 1.f : 0.f;
        #pragma unroll
        for (int j = 0; j < 8; ++j)
            acc[j] += m * bf2f((ushort)v[j]);
    }

    #pragma unroll
    for (int j = 0; j < 8; ++j) {
        float t = acc[j];
        t += __shfl_xor(t, 16, 64);
        t += __shfl_xor(t, 32, 64);
        acc[j] = t;
    }
    if (g == 0) {
        float inv = 1.0f / fmaxf((float)(e2 - b), 1.0f);
        short8 o;
        #pragma unroll
        for (int j = 0; j < 8; ++j) o[j] = (short)f2bf(acc[j] * inv);
        *(short8*)(agg1 + node * 128 + sub * 8) = o;
    }
}

// ---------------- dense0: h0 = relu([agg0|x] @ [Wl0;Wr0]^T + bl0), MFMA ----------------
__global__ __launch_bounds__(256) void dense0_k(
    const ushort* __restrict__ xb, const ushort* __restrict__ agg0,
    const ushort* __restrict__ wbt0, const float* __restrict__ bl,
    ushort* __restrict__ h0)
{
    __shared__ ushort bt[128 * 128];
    __shared__ float  bl_s[128];

    #pragma unroll
    for (int c = 0; c < 8; ++c) {
        int i = threadIdx.x + c * 256;
        ((short8*)bt)[i] = ((const short8*)wbt0)[i];
    }
    if (threadIdx.x < 128) bl_s[threadIdx.x] = bl[threadIdx.x];
    __syncthreads();

    int w = threadIdx.x >> 6, l = threadIdx.x & 63;
    int l15 = l & 15, hi = l >> 4;
    int row  = blockIdx.x * 64 + w * 16 + l15;
    int rowc = row < NN ? row : 0;

    short8 a[4];
    a[0] = *(const short8*)(agg0 + rowc * 64 + hi * 8);
    a[1] = *(const short8*)(agg0 + rowc * 64 + 32 + hi * 8);
    a[2] = *(const short8*)(xb + rowc * 64 + hi * 8);
    a[3] = *(const short8*)(xb + rowc * 64 + 32 + hi * 8);

    f32x4 acc[8];
    #pragma unroll
    for (int nt = 0; nt < 8; ++nt) acc[nt] = (f32x4){0.f, 0.f, 0.f, 0.f};

    #pragma unroll
    for (int ks = 0; ks < 4; ++ks) {
        #pragma unroll
        for (int nt = 0; nt < 8; ++nt) {
            int byte = ((nt * 16 + l15) * 256 + (ks * 32 + hi * 8) * 2) ^ ((l15 & 7) << 4);
            short8 bfr = *(const short8*)((const char*)bt + byte);
            acc[nt] = __builtin_amdgcn_mfma_f32_16x16x32_bf16(a[ks], bfr, acc[nt], 0, 0, 0);
        }
    }

    int rowbase = blockIdx.x * 64 + w * 16 + hi * 4;
    #pragma unroll
    for (int r = 0; r < 4; ++r) {
        int ro = rowbase + r;
        if (ro < NN) {
            #pragma unroll
            for (int nt = 0; nt < 8; ++nt) {
                int col = nt * 16 + l15;
                float v = fmaxf(acc[nt][r] + bl_s[col], 0.f);
                h0[ro * 128 + col] = f2bf(v);
            }
        }
    }
}

// ---------------- dense1 + fc fused ----------------
__global__ __launch_bounds__(256) void dense1_k(
    const ushort* __restrict__ h0, const ushort* __restrict__ agg1,
    const ushort* __restrict__ wbt1, const float* __restrict__ bl,
    const float* __restrict__ Wfc, const float* __restrict__ bfc,
    float* __restrict__ out)
{
    __shared__ ushort bt[256 * 128];
    __shared__ float  bl_s[128];
    __shared__ float  wfc_s[256];

    #pragma unroll
    for (int c = 0; c < 16; ++c) {
        int i = threadIdx.x + c * 256;
        ((short8*)bt)[i] = ((const short8*)wbt1)[i];
    }
    if (threadIdx.x < 128) bl_s[threadIdx.x] = bl[threadIdx.x];
    if (threadIdx.x < 256) wfc_s[threadIdx.x] = Wfc[threadIdx.x];
    __syncthreads();

    int w = threadIdx.x >> 6, l = threadIdx.x & 63;
    int l15 = l & 15, hi = l >> 4;
    int row  = blockIdx.x * 64 + w * 16 + l15;
    int rowc = row < NN ? row : 0;

    short8 a[8];
    #pragma unroll
    for (int ks = 0; ks < 4; ++ks)
        a[ks] = *(const short8*)(agg1 + rowc * 128 + ks * 32 + hi * 8);
    #pragma unroll
    for (int ks = 0; ks < 4; ++ks)
        a[4 + ks] = *(const short8*)(h0 + rowc * 128 + ks * 32 + hi * 8);

    f32x4 acc[8];
    #pragma unroll
    for (int nt = 0; nt < 8; ++nt) acc[nt] = (f32x4){0.f, 0.f, 0.f, 0.f};

    #pragma unroll
    for (int ks = 0; ks < 8; ++ks) {
        #pragma unroll
        for (int nt = 0; nt < 8; ++nt) {
            int byte = ((nt * 16 + l15) * 512 + (ks * 32 + hi * 8) * 2) ^ ((l15 & 7) << 4);
            short8 bfr = *(const short8*)((const char*)bt + byte);
            acc[nt] = __builtin_amdgcn_mfma_f32_16x16x32_bf16(a[ks], bfr, acc[nt], 0, 0, 0);
        }
    }

    int rowbase = blockIdx.x * 64 + w * 16 + hi * 4;
    #pragma unroll
    for (int r = 0; r < 4; ++r) {
        float p0 = 0.f, p1 = 0.f;
        #pragma unroll
        for (int nt = 0; nt < 8; ++nt) {
            int col = nt * 16 + l15;
            float h1 = fmaxf(acc[nt][r] + bl_s[col], 0.f);
            p0 += h1 * wfc_s[col];
            p1 += h1 * wfc_s[128 + col];
        }
        p0 += __shfl_xor(p0, 1, 64); p0 += __shfl_xor(p0, 2, 64);
        p0 += __shfl_xor(p0, 4, 64); p0 += __shfl_xor(p0, 8, 64);
        p1 += __shfl_xor(p1, 1, 64); p1 += __shfl_xor(p1, 2, 64);
        p1 += __shfl_xor(p1, 4, 64); p1 += __shfl_xor(p1, 8, 64);
        int ro = rowbase + r;
        if (l15 == 0 && ro < NN) {
            float2 o; o.x = p0 + bfc[0]; o.y = p1 + bfc[1];
            *(float2*)(out + ro * 2) = o;
        }
    }
}

extern "C" void kernel_launch(void* const* d_in, const int* in_sizes, int n_in,
                              void* d_out, int out_size, void* d_ws, size_t ws_size,
                              hipStream_t stream)
{
    const float* x   = (const float*)d_in[0];
    const int*   ei  = (const int*)d_in[1];
    const float* Wl0 = (const float*)d_in[2];
    const float* bl0 = (const float*)d_in[3];
    const float* Wr0 = (const float*)d_in[4];
    const float* Wl1 = (const float*)d_in[5];
    const float* bl1 = (const float*)d_in[6];
    const float* Wr1 = (const float*)d_in[7];
    const float* Wfc = (const float*)d_in[8];
    const float* bfc = (const float*)d_in[9];
    float* out = (float*)d_out;

    const int* src = ei;
    const int* dst = ei + NE;

    // ws layout (bytes):
    //   deg    @ 0          (200,000)   \ one memset covers both
    //   state  @ 200,000    (2,048)     /
    //   rowptr @ 202,048    (200,004)
    //   rank   @ 402,052    (3,200,000)
    //   nbr    @ 3,602,052  (3,200,000)
    //   aggB   @ 6,802,064  (12,800,000)
    //   h0B    @ 19,602,064 (12,800,000)
    //   xb     @ 32,402,064 (6,400,000)
    //   wbt0   @ 38,802,064 (32,768)
    //   wbt1   @ 38,834,832 (65,536)
    char*   ws     = (char*)d_ws;
    int*    deg    = (int*)(ws);
    unsigned long long* state = (unsigned long long*)(ws + 200000);
    int*    rowptr = (int*)(ws + 202048);
    int*    rank   = (int*)(ws + 402052);
    int*    nbr    = (int*)(ws + 3602052);
    ushort* aggB   = (ushort*)(ws + 6802064);
    ushort* h0B    = (ushort*)(ws + 19602064);
    ushort* xb     = (ushort*)(ws + 32402064);
    ushort* wbt0   = (ushort*)(ws + 38802064);
    ushort* wbt1   = (ushort*)(ws + 38834832);

    hipMemsetAsync(deg, 0, 202048, stream);   // deg + scan state

    count_k <<<3125, 256, 0, stream>>>(dst, deg, rank, x, xb,
                                       Wl0, Wr0, Wl1, Wr1, wbt0, wbt1);
    scan_k  <<<NB, 256, 0, stream>>>(deg, state, rowptr);
    fill_k  <<<3125, 256, 0, stream>>>(src, dst, rowptr, rank, nbr);

    gather0_k<<<12500, 256, 0, stream>>>(xb, rowptr, nbr, aggB);
    dense0_k <<<782, 256, 0, stream>>>(xb, aggB, wbt0, bl0, h0B);
    gather1_k<<<12500, 256, 0, stream>>>(h0B, rowptr, nbr, aggB);
    dense1_k <<<782, 256, 0, stream>>>(h0B, aggB, wbt1, bl1, Wfc, bfc, out);
}

// Round 11
// 140.831 us; speedup vs baseline: 6.1429x; 1.0646x over previous
//
#include <hip/hip_runtime.h>
#include <hip/hip_bf16.h>

#define NN   50000
#define NE   800000
#define NB   196   // ceil(NN/256)

typedef __attribute__((ext_vector_type(8))) short short8;
typedef __attribute__((ext_vector_type(4))) float f32x4;

static __device__ __forceinline__ ushort f2bf(float f) {
    union { float f; unsigned u; } v; v.f = f;
    unsigned r = v.u + 0x7fffu + ((v.u >> 16) & 1u);   // round-to-nearest-even
    return (ushort)(r >> 16);
}
static __device__ __forceinline__ float bf2f(ushort h) {
    union { unsigned u; float f; } v; v.u = ((unsigned)h) << 16;
    return v.f;
}

// ---------------- count (+rank) + x->bf16 + weight-image prep ----------------
__global__ __launch_bounds__(256) void count_k(
    const int* __restrict__ dst, int* __restrict__ deg,
    int* __restrict__ rank,
    const float* __restrict__ x, ushort* __restrict__ xb,
    const float* __restrict__ Wl0, const float* __restrict__ Wr0,
    const float* __restrict__ Wl1, const float* __restrict__ Wr1,
    ushort* __restrict__ wbt0, ushort* __restrict__ wbt1)
{
    int gid = blockIdx.x * 256 + threadIdx.x;

    if (gid < 2048) {
        {   // dense0 image
            int c = gid;
            int n  = c >> 4;
            int kc = (c & 15) * 8;
            const float* wsrc = (kc < 64) ? (Wl0 + n * 64 + kc) : (Wr0 + n * 64 + (kc - 64));
            float4 f0 = *(const float4*)(wsrc);
            float4 f1 = *(const float4*)(wsrc + 4);
            short8 v;
            v[0] = f2bf(f0.x); v[1] = f2bf(f0.y); v[2] = f2bf(f0.z); v[3] = f2bf(f0.w);
            v[4] = f2bf(f1.x); v[5] = f2bf(f1.y); v[6] = f2bf(f1.z); v[7] = f2bf(f1.w);
            int byte = (n * 256 + kc * 2) ^ ((n & 7) << 4);
            *(short8*)((char*)wbt0 + byte) = v;
        }
        #pragma unroll
        for (int rep = 0; rep < 2; ++rep) {   // dense1 image
            int c = gid + rep * 2048;
            int n  = c >> 5;
            int kc = (c & 31) * 8;
            const float* wsrc = (kc < 128) ? (Wl1 + n * 128 + kc) : (Wr1 + n * 128 + (kc - 128));
            float4 f0 = *(const float4*)(wsrc);
            float4 f1 = *(const float4*)(wsrc + 4);
            short8 v;
            v[0] = f2bf(f0.x); v[1] = f2bf(f0.y); v[2] = f2bf(f0.z); v[3] = f2bf(f0.w);
            v[4] = f2bf(f1.x); v[5] = f2bf(f1.y); v[6] = f2bf(f1.z); v[7] = f2bf(f1.w);
            int byte = (n * 512 + kc * 2) ^ ((n & 7) << 4);
            *(short8*)((char*)wbt1 + byte) = v;
        }
    }

    int base = gid * 4;
    float4 f = *(const float4*)(x + base);
    ushort4 o;
    o.x = f2bf(f.x); o.y = f2bf(f.y); o.z = f2bf(f.z); o.w = f2bf(f.w);
    *(ushort4*)(xb + base) = o;

    int d = dst[gid];
    rank[gid] = atomicAdd(&deg[d], 1);
}

__global__ __launch_bounds__(256) void partial_k(
    const int* __restrict__ deg, int* __restrict__ bsum)
{
    int gid = blockIdx.x * 256 + threadIdx.x;
    int v = (gid < NN) ? deg[gid] : 0;
    #pragma unroll
    for (int off = 32; off > 0; off >>= 1) v += __shfl_xor(v, off, 64);
    __shared__ int wsum[4];
    if ((threadIdx.x & 63) == 0) wsum[threadIdx.x >> 6] = v;
    __syncthreads();
    if (threadIdx.x == 0)
        bsum[blockIdx.x] = wsum[0] + wsum[1] + wsum[2] + wsum[3];
}

__global__ __launch_bounds__(256) void emit_k(
    const int* __restrict__ deg, const int* __restrict__ bsum,
    int* __restrict__ rowptr)
{
    __shared__ int s[256], sb[256];
    int tid = threadIdx.x;
    int gid = blockIdx.x * 256 + tid;
    int v  = (gid < NN) ? deg[gid] : 0;
    int bv = (tid < NB) ? bsum[tid] : 0;
    s[tid] = v; sb[tid] = bv;
    __syncthreads();
    for (int off = 1; off < 256; off <<= 1) {
        int a1 = (tid >= off) ? s[tid - off] : 0;
        int a2 = (tid >= off) ? sb[tid - off] : 0;
        __syncthreads();
        s[tid] += a1; sb[tid] += a2;
        __syncthreads();
    }
    int boff = (blockIdx.x == 0) ? 0 : sb[blockIdx.x - 1];
    if (gid < NN) rowptr[gid] = boff + s[tid] - v;
    if (blockIdx.x == 0 && tid == 0) rowptr[NN] = NE;
}

__global__ __launch_bounds__(256) void fill_k(
    const int* __restrict__ src, const int* __restrict__ dst,
    const int* __restrict__ rowptr, const int* __restrict__ rank,
    int* __restrict__ nbr)
{
    int e = blockIdx.x * 256 + threadIdx.x;
    int d = dst[e];
    nbr[rowptr[d] + rank[e]] = src[e];
}

// ---------------- gather0: one node per 8-lane group, 4-deep MLP ----------------
// 32 nodes per block (256 threads). No shfl reduce, no masked dead loads.
__global__ __launch_bounds__(256) void gather0_k(
    const ushort* __restrict__ xb, const int* __restrict__ rowptr,
    const int* __restrict__ nbr, ushort* __restrict__ agg0)
{
    int node = (blockIdx.x * 256 + threadIdx.x) >> 3;
    int sub  = threadIdx.x & 7;          // feature octet 0..7
    if (node >= NN) return;
    int b = rowptr[node], e2 = rowptr[node + 1];
    float acc[8];
    #pragma unroll
    for (int j = 0; j < 8; ++j) acc[j] = 0.f;

    int e = b;
    for (; e + 4 <= e2; e += 4) {
        int s0 = nbr[e], s1 = nbr[e + 1], s2 = nbr[e + 2], s3 = nbr[e + 3];
        short8 v0 = *(const short8*)(xb + s0 * 64 + sub * 8);
        short8 v1 = *(const short8*)(xb + s1 * 64 + sub * 8);
        short8 v2 = *(const short8*)(xb + s2 * 64 + sub * 8);
        short8 v3 = *(const short8*)(xb + s3 * 64 + sub * 8);
        #pragma unroll
        for (int j = 0; j < 8; ++j)
            acc[j] += (bf2f((ushort)v0[j]) + bf2f((ushort)v1[j]))
                    + (bf2f((ushort)v2[j]) + bf2f((ushort)v3[j]));
    }
    for (; e < e2; ++e) {
        int s = nbr[e];
        short8 v = *(const short8*)(xb + s * 64 + sub * 8);
        #pragma unroll
        for (int j = 0; j < 8; ++j) acc[j] += bf2f((ushort)v[j]);
    }

    float inv = 1.0f / fmaxf((float)(e2 - b), 1.0f);
    short8 o;
    #pragma unroll
    for (int j = 0; j < 8; ++j) o[j] = (short)f2bf(acc[j] * inv);
    *(short8*)(agg0 + node * 64 + sub * 8) = o;
}

// ---------------- gather1: one node per 16-lane group, 4-deep MLP ----------------
// 16 nodes per block.
__global__ __launch_bounds__(256) void gather1_k(
    const ushort* __restrict__ h0, const int* __restrict__ rowptr,
    const int* __restrict__ nbr, ushort* __restrict__ agg1)
{
    int node = (blockIdx.x * 256 + threadIdx.x) >> 4;
    int sub  = threadIdx.x & 15;         // feature octet 0..15
    if (node >= NN) return;
    int b = rowptr[node], e2 = rowptr[node + 1];
    float acc[8];
    #pragma unroll
    for (int j = 0; j < 8; ++j) acc[j] = 0.f;

    int e = b;
    for (; e + 4 <= e2; e += 4) {
        int s0 = nbr[e], s1 = nbr[e + 1], s2 = nbr[e + 2], s3 = nbr[e + 3];
        short8 v0 = *(const short8*)(h0 + s0 * 128 + sub * 8);
        short8 v1 = *(const short8*)(h0 + s1 * 128 + sub * 8);
        short8 v2 = *(const short8*)(h0 + s2 * 128 + sub * 8);
        short8 v3 = *(const short8*)(h0 + s3 * 128 + sub * 8);
        #pragma unroll
        for (int j = 0; j < 8; ++j)
            acc[j] += (bf2f((ushort)v0[j]) + bf2f((ushort)v1[j]))
                    + (bf2f((ushort)v2[j]) + bf2f((ushort)v3[j]));
    }
    for (; e < e2; ++e) {
        int s = nbr[e];
        short8 v = *(const short8*)(h0 + s * 128 + sub * 8);
        #pragma unroll
        for (int j = 0; j < 8; ++j) acc[j] += bf2f((ushort)v[j]);
    }

    float inv = 1.0f / fmaxf((float)(e2 - b), 1.0f);
    short8 o;
    #pragma unroll
    for (int j = 0; j < 8; ++j) o[j] = (short)f2bf(acc[j] * inv);
    *(short8*)(agg1 + node * 128 + sub * 8) = o;
}

// ---------------- dense0: h0 = relu([agg0|x] @ [Wl0;Wr0]^T + bl0), MFMA ----------------
__global__ __launch_bounds__(256) void dense0_k(
    const ushort* __restrict__ xb, const ushort* __restrict__ agg0,
    const ushort* __restrict__ wbt0, const float* __restrict__ bl,
    ushort* __restrict__ h0)
{
    __shared__ ushort bt[128 * 128];
    __shared__ float  bl_s[128];

    #pragma unroll
    for (int c = 0; c < 8; ++c) {
        int i = threadIdx.x + c * 256;
        ((short8*)bt)[i] = ((const short8*)wbt0)[i];
    }
    if (threadIdx.x < 128) bl_s[threadIdx.x] = bl[threadIdx.x];
    __syncthreads();

    int w = threadIdx.x >> 6, l = threadIdx.x & 63;
    int l15 = l & 15, hi = l >> 4;
    int row  = blockIdx.x * 64 + w * 16 + l15;
    int rowc = row < NN ? row : 0;

    short8 a[4];
    a[0] = *(const short8*)(agg0 + rowc * 64 + hi * 8);
    a[1] = *(const short8*)(agg0 + rowc * 64 + 32 + hi * 8);
    a[2] = *(const short8*)(xb + rowc * 64 + hi * 8);
    a[3] = *(const short8*)(xb + rowc * 64 + 32 + hi * 8);

    f32x4 acc[8];
    #pragma unroll
    for (int nt = 0; nt < 8; ++nt) acc[nt] = (f32x4){0.f, 0.f, 0.f, 0.f};

    #pragma unroll
    for (int ks = 0; ks < 4; ++ks) {
        #pragma unroll
        for (int nt = 0; nt < 8; ++nt) {
            int byte = ((nt * 16 + l15) * 256 + (ks * 32 + hi * 8) * 2) ^ ((l15 & 7) << 4);
            short8 bfr = *(const short8*)((const char*)bt + byte);
            acc[nt] = __builtin_amdgcn_mfma_f32_16x16x32_bf16(a[ks], bfr, acc[nt], 0, 0, 0);
        }
    }

    int rowbase = blockIdx.x * 64 + w * 16 + hi * 4;
    #pragma unroll
    for (int r = 0; r < 4; ++r) {
        int ro = rowbase + r;
        if (ro < NN) {
            #pragma unroll
            for (int nt = 0; nt < 8; ++nt) {
                int col = nt * 16 + l15;
                float v = fmaxf(acc[nt][r] + bl_s[col], 0.f);
                h0[ro * 128 + col] = f2bf(v);
            }
        }
    }
}

// ---------------- dense1 + fc fused ----------------
__global__ __launch_bounds__(256) void dense1_k(
    const ushort* __restrict__ h0, const ushort* __restrict__ agg1,
    const ushort* __restrict__ wbt1, const float* __restrict__ bl,
    const float* __restrict__ Wfc, const float* __restrict__ bfc,
    float* __restrict__ out)
{
    __shared__ ushort bt[256 * 128];
    __shared__ float  bl_s[128];
    __shared__ float  wfc_s[256];

    #pragma unroll
    for (int c = 0; c < 16; ++c) {
        int i = threadIdx.x + c * 256;
        ((short8*)bt)[i] = ((const short8*)wbt1)[i];
    }
    if (threadIdx.x < 128) bl_s[threadIdx.x] = bl[threadIdx.x];
    if (threadIdx.x < 256) wfc_s[threadIdx.x] = Wfc[threadIdx.x];
    __syncthreads();

    int w = threadIdx.x >> 6, l = threadIdx.x & 63;
    int l15 = l & 15, hi = l >> 4;
    int row  = blockIdx.x * 64 + w * 16 + l15;
    int rowc = row < NN ? row : 0;

    short8 a[8];
    #pragma unroll
    for (int ks = 0; ks < 4; ++ks)
        a[ks] = *(const short8*)(agg1 + rowc * 128 + ks * 32 + hi * 8);
    #pragma unroll
    for (int ks = 0; ks < 4; ++ks)
        a[4 + ks] = *(const short8*)(h0 + rowc * 128 + ks * 32 + hi * 8);

    f32x4 acc[8];
    #pragma unroll
    for (int nt = 0; nt < 8; ++nt) acc[nt] = (f32x4){0.f, 0.f, 0.f, 0.f};

    #pragma unroll
    for (int ks = 0; ks < 8; ++ks) {
        #pragma unroll
        for (int nt = 0; nt < 8; ++nt) {
            int byte = ((nt * 16 + l15) * 512 + (ks * 32 + hi * 8) * 2) ^ ((l15 & 7) << 4);
            short8 bfr = *(const short8*)((const char*)bt + byte);
            acc[nt] = __builtin_amdgcn_mfma_f32_16x16x32_bf16(a[ks], bfr, acc[nt], 0, 0, 0);
        }
    }

    int rowbase = blockIdx.x * 64 + w * 16 + hi * 4;
    #pragma unroll
    for (int r = 0; r < 4; ++r) {
        float p0 = 0.f, p1 = 0.f;
        #pragma unroll
        for (int nt = 0; nt < 8; ++nt) {
            int col = nt * 16 + l15;
            float h1 = fmaxf(acc[nt][r] + bl_s[col], 0.f);
            p0 += h1 * wfc_s[col];
            p1 += h1 * wfc_s[128 + col];
        }
        p0 += __shfl_xor(p0, 1, 64); p0 += __shfl_xor(p0, 2, 64);
        p0 += __shfl_xor(p0, 4, 64); p0 += __shfl_xor(p0, 8, 64);
        p1 += __shfl_xor(p1, 1, 64); p1 += __shfl_xor(p1, 2, 64);
        p1 += __shfl_xor(p1, 4, 64); p1 += __shfl_xor(p1, 8, 64);
        int ro = rowbase + r;
        if (l15 == 0 && ro < NN) {
            float2 o; o.x = p0 + bfc[0]; o.y = p1 + bfc[1];
            *(float2*)(out + ro * 2) = o;
        }
    }
}

extern "C" void kernel_launch(void* const* d_in, const int* in_sizes, int n_in,
                              void* d_out, int out_size, void* d_ws, size_t ws_size,
                              hipStream_t stream)
{
    const float* x   = (const float*)d_in[0];
    const int*   ei  = (const int*)d_in[1];
    const float* Wl0 = (const float*)d_in[2];
    const float* bl0 = (const float*)d_in[3];
    const float* Wr0 = (const float*)d_in[4];
    const float* Wl1 = (const float*)d_in[5];
    const float* bl1 = (const float*)d_in[6];
    const float* Wr1 = (const float*)d_in[7];
    const float* Wfc = (const float*)d_in[8];
    const float* bfc = (const float*)d_in[9];
    float* out = (float*)d_out;

    const int* src = ei;
    const int* dst = ei + NE;

    // ws layout (bytes):
    //   deg    @ 0          (200,000)   <- memset
    //   rowptr @ 200,000    (200,004)
    //   rank   @ 400,004    (3,200,000)
    //   nbr    @ 3,600,004  (3,200,000)
    //   aggB   @ 6,800,016  (12,800,000)
    //   h0B    @ 19,600,016 (12,800,000)
    //   bsum   @ 32,400,016 (784)
    //   xb     @ 32,401,600 (6,400,000)
    //   wbt0   @ 38,801,600 (32,768)
    //   wbt1   @ 38,834,368 (65,536)
    char*   ws     = (char*)d_ws;
    int*    deg    = (int*)(ws);
    int*    rowptr = (int*)(ws + 200000);
    int*    rank   = (int*)(ws + 400004);
    int*    nbr    = (int*)(ws + 3600004);
    ushort* aggB   = (ushort*)(ws + 6800016);
    ushort* h0B    = (ushort*)(ws + 19600016);
    int*    bsum   = (int*)(ws + 32400016);
    ushort* xb     = (ushort*)(ws + 32401600);
    ushort* wbt0   = (ushort*)(ws + 38801600);
    ushort* wbt1   = (ushort*)(ws + 38834368);

    hipMemsetAsync(deg, 0, 200000, stream);

    count_k  <<<3125, 256, 0, stream>>>(dst, deg, rank, x, xb,
                                        Wl0, Wr0, Wl1, Wr1, wbt0, wbt1);
    partial_k<<<NB, 256, 0, stream>>>(deg, bsum);
    emit_k   <<<NB, 256, 0, stream>>>(deg, bsum, rowptr);
    fill_k   <<<3125, 256, 0, stream>>>(src, dst, rowptr, rank, nbr);

    gather0_k<<<1563, 256, 0, stream>>>(xb, rowptr, nbr, aggB);
    dense0_k <<<782, 256, 0, stream>>>(xb, aggB, wbt0, bl0, h0B);
    gather1_k<<<3125, 256, 0, stream>>>(h0B, rowptr, nbr, aggB);
    dense1_k <<<782, 256, 0, stream>>>(h0B, aggB, wbt1, bl1, Wfc, bfc, out);
}